// Round 1
// baseline (690.908 us; speedup 1.0000x reference)
//
#include <hip/hip_runtime.h>
#include <math.h>

#define DEV_INLINE __device__ __forceinline__

DEV_INLINE float sigmoidf_(float x) { return 1.0f / (1.0f + expf(-x)); }

// ---- column-reduction GEMV: out[0..1024) += sum_{r in [r0,r1)} A[r,:] * x[r]
// A is (rows x 1024) row-major. Block = 256 threads, each owns 4 consecutive cols.
DEV_INLINE void colgemv_block(const float* __restrict__ A, const float* __restrict__ x,
                              float* __restrict__ out, int r0, int r1) {
    int c4 = threadIdx.x;                       // 0..255 -> cols 4*c4..4*c4+3
    const float4* A4 = (const float4*)A;
    float4 acc = make_float4(0.f, 0.f, 0.f, 0.f);
    for (int r = r0; r < r1; ++r) {
        float xv = x[r];                        // broadcast load
        float4 a = A4[(size_t)r * 256 + c4];    // coalesced: full 4KB row per block step
        acc.x = fmaf(xv, a.x, acc.x);
        acc.y = fmaf(xv, a.y, acc.y);
        acc.z = fmaf(xv, a.z, acc.z);
        acc.w = fmaf(xv, a.w, acc.w);
    }
    int c = c4 * 4;
    atomicAdd(out + c + 0, acc.x);
    atomicAdd(out + c + 1, acc.y);
    atomicAdd(out + c + 2, acc.z);
    atomicAdd(out + c + 3, acc.w);
}

// ---- row dot: one wave computes dot(row, x) over nv float4 elements
DEV_INLINE float wave_dot(const float* __restrict__ row, const float* __restrict__ x,
                          int nv, int lane) {
    const float4* r4 = (const float4*)row;
    const float4* x4 = (const float4*)x;
    float acc = 0.f;
    for (int i = lane; i < nv; i += 64) {
        float4 a = r4[i], b = x4[i];
        acc = fmaf(a.x, b.x, fmaf(a.y, b.y, fmaf(a.z, b.z, fmaf(a.w, b.w, acc))));
    }
#pragma unroll
    for (int off = 32; off; off >>= 1) acc += __shfl_down(acc, off, 64);
    return acc;  // valid in lane 0
}

// ===== Phase A: everything that depends only on y and s (~460 MB of reads) =====
// blocks [0,128): W^T y -> acc_st   (16000x1024, chunk 125)
// [128,256): Wz^T y -> acc_z
// [256,384): Wr^T y -> acc_r
// [384,392): Uz^T s -> acc_z        (1024x1024, chunk 128)
// [392,400): Ur^T s -> acc_r
// [400,1424): Vo @ y -> acc_t       (4096 rows x 16000, wave per row)
// [1424,1437): Wa @ s -> ws50       (50 rows x 1024)
__global__ void k_phaseA(const float* __restrict__ W, const float* __restrict__ Wz,
                         const float* __restrict__ Wr, const float* __restrict__ Uz,
                         const float* __restrict__ Ur, const float* __restrict__ Vo,
                         const float* __restrict__ Wa, const float* __restrict__ y,
                         const float* __restrict__ s, float* acc_r, float* acc_z,
                         float* acc_st, float* acc_t, float* ws50) {
    int b = blockIdx.x;
    if (b < 128) { colgemv_block(W, y, acc_st, b * 125, b * 125 + 125); return; }
    b -= 128;
    if (b < 128) { colgemv_block(Wz, y, acc_z, b * 125, b * 125 + 125); return; }
    b -= 128;
    if (b < 128) { colgemv_block(Wr, y, acc_r, b * 125, b * 125 + 125); return; }
    b -= 128;
    if (b < 8) { colgemv_block(Uz, s, acc_z, b * 128, b * 128 + 128); return; }
    b -= 8;
    if (b < 8) { colgemv_block(Ur, s, acc_r, b * 128, b * 128 + 128); return; }
    b -= 8;
    if (b < 1024) {
        int wid = (b * 256 + threadIdx.x) >> 6;
        int lane = threadIdx.x & 63;
        float v = wave_dot(Vo + (size_t)wid * 16000, y, 4000, lane);
        if (lane == 0) acc_t[wid] = v;  // acc_t zeroed; Uo/Co add later
        return;
    }
    b -= 1024;
    {
        int wid = (b * 256 + threadIdx.x) >> 6;
        int lane = threadIdx.x & 63;
        if (wid < 50) {
            float v = wave_dot(Wa + wid * 1024, s, 256, lane);
            if (lane == 0) ws50[wid] = v;
        }
    }
}

// e[i,j] = tanh(ws50[j] + dot(h_row_i, Ua_row_j)); 2500 waves
__global__ void k_escore(const float* __restrict__ h, const float* __restrict__ Ua,
                         const float* __restrict__ ws50, float* __restrict__ em) {
    int wid = (blockIdx.x * blockDim.x + threadIdx.x) >> 6;
    int lane = threadIdx.x & 63;
    if (wid >= 2500) return;
    int i = wid / 50, j = wid - i * 50;
    float d = wave_dot(h + i * 2048, Ua + j * 2048, 512, lane);
    if (lane == 0) em[wid] = tanhf(ws50[j] + d);
}

// each block (8 blocks x 256): recompute attn (cheap) then alpha + c columns
__global__ void k_alpha_c(const float* __restrict__ h, const float* __restrict__ Va,
                          const float* __restrict__ em, float* __restrict__ cvec,
                          float* __restrict__ alpha_out) {
    __shared__ float attn_s[50];
    int tid = threadIdx.x;
    if (tid < 64) {
        float sc = -1e30f;
        if (tid < 50) {
            float t = 0.f;
            for (int j = 0; j < 50; ++j) t = fmaf(Va[j], em[tid * 50 + j], t);
            sc = t;
        }
        float m = sc;
#pragma unroll
        for (int off = 32; off; off >>= 1) m = fmaxf(m, __shfl_xor(m, off, 64));
        float e = (tid < 50) ? expf(sc - m) : 0.f;
        float ssum = e;
#pragma unroll
        for (int off = 32; off; off >>= 1) ssum += __shfl_xor(ssum, off, 64);
        if (tid < 50) attn_s[tid] = e / ssum;
    }
    __syncthreads();
    int g = blockIdx.x * 256 + tid;  // < 2048
    float csum = 0.f;
    for (int i = 0; i < 50; ++i) {
        float a = h[i * 2048 + g] * attn_s[i];
        alpha_out[i * 2048 + g] = a;
        csum += a;
    }
    cvec[g] = csum;
}

// C^T c -> acc_st, Cz^T c -> acc_z, Cr^T c -> acc_r  (2048x1024 each)
__global__ void k_phaseB(const float* __restrict__ C, const float* __restrict__ Cz,
                         const float* __restrict__ Cr, const float* __restrict__ cvec,
                         float* acc_st, float* acc_z, float* acc_r) {
    int b = blockIdx.x;
    if (b < 16) { colgemv_block(C, cvec, acc_st, b * 128, b * 128 + 128); return; }
    b -= 16;
    if (b < 16) { colgemv_block(Cz, cvec, acc_z, b * 128, b * 128 + 128); return; }
    b -= 16;
    colgemv_block(Cr, cvec, acc_r, b * 128, b * 128 + 128);
}

__global__ void k_rz(const float* __restrict__ acc_r, const float* __restrict__ acc_z,
                     const float* __restrict__ s, float* __restrict__ rs,
                     float* __restrict__ zbuf) {
    int n = blockIdx.x * 256 + threadIdx.x;
    float r = sigmoidf_(acc_r[n]);
    zbuf[n] = sigmoidf_(acc_z[n]);
    rs[n] = r * s[n];
}

__global__ void k_Ust(const float* __restrict__ U, const float* __restrict__ rs,
                      float* acc_st) {
    int b = blockIdx.x;
    colgemv_block(U, rs, acc_st, b * 128, b * 128 + 128);
}

__global__ void k_snew(const float* __restrict__ acc_st, const float* __restrict__ zbuf,
                       const float* __restrict__ s, float* __restrict__ snew,
                       float* __restrict__ out_snew) {
    int n = blockIdx.x * 256 + threadIdx.x;
    float st = sigmoidf_(acc_st[n]);
    float z = zbuf[n];
    float v = (1.f - z) * s[n] + z * st;
    snew[n] = v;
    out_snew[n] = v;
}

// acc_t[r] += Uo[r,:]@snew + Co[r,:]@c   (4096 rows)
__global__ void k_uoco(const float* __restrict__ Uo, const float* __restrict__ Co,
                       const float* __restrict__ snew, const float* __restrict__ cvec,
                       float* __restrict__ acc_t) {
    int wid = (blockIdx.x * 256 + threadIdx.x) >> 6;
    int lane = threadIdx.x & 63;
    float d1 = wave_dot(Uo + (size_t)wid * 1024, snew, 256, lane);
    float d2 = wave_dot(Co + (size_t)wid * 2048, cvec, 512, lane);
    if (lane == 0) acc_t[wid] += d1 + d2;
}

__global__ void k_tmax(const float* __restrict__ acc_t, float* __restrict__ tvec) {
    int k = blockIdx.x * 256 + threadIdx.x;
    tvec[k] = fmaxf(sigmoidf_(acc_t[2 * k]), sigmoidf_(acc_t[2 * k + 1]));
}

// logits[m] = Wo[m,:] @ t  -> written straight into d_out[0..16000)
__global__ void k_wo(const float* __restrict__ Wo, const float* __restrict__ tvec,
                     float* __restrict__ logits) {
    int wid = (blockIdx.x * 256 + threadIdx.x) >> 6;
    int lane = threadIdx.x & 63;
    float v = wave_dot(Wo + (size_t)wid * 2048, tvec, 512, lane);
    if (lane == 0) logits[wid] = v;
}

// in-place log_softmax over d_out[0..16000), single block 1024 threads
__global__ void k_logsm(float* __restrict__ out) {
    __shared__ float red[16];
    __shared__ float bval;
    int tid = threadIdx.x, lane = tid & 63, w = tid >> 6;
    float m = -1e30f;
    for (int i = tid; i < 16000; i += 1024) m = fmaxf(m, out[i]);
#pragma unroll
    for (int off = 32; off; off >>= 1) m = fmaxf(m, __shfl_xor(m, off, 64));
    if (lane == 0) red[w] = m;
    __syncthreads();
    if (tid == 0) {
        float mm = red[0];
        for (int i = 1; i < 16; ++i) mm = fmaxf(mm, red[i]);
        bval = mm;
    }
    __syncthreads();
    float M = bval;
    float sum = 0.f;
    for (int i = tid; i < 16000; i += 1024) sum += expf(out[i] - M);
#pragma unroll
    for (int off = 32; off; off >>= 1) sum += __shfl_xor(sum, off, 64);
    if (lane == 0) red[w] = sum;
    __syncthreads();
    if (tid == 0) {
        float ss = 0.f;
        for (int i = 0; i < 16; ++i) ss += red[i];
        bval = M + logf(ss);
    }
    __syncthreads();
    float lse = bval;
    for (int i = tid; i < 16000; i += 1024) out[i] -= lse;
}

extern "C" void kernel_launch(void* const* d_in, const int* in_sizes, int n_in,
                              void* d_out, int out_size, void* d_ws, size_t ws_size,
                              hipStream_t stream) {
    const float* y  = (const float*)d_in[0];   // output (M,1)
    const float* s  = (const float*)d_in[1];   // hidden (N,1)
    const float* h  = (const float*)d_in[2];   // encoder_outputs (T,2N)
    const float* W  = (const float*)d_in[3];
    const float* Wz = (const float*)d_in[4];
    const float* Wr = (const float*)d_in[5];
    const float* Wo = (const float*)d_in[6];
    const float* U  = (const float*)d_in[7];
    const float* Uz = (const float*)d_in[8];
    const float* Ur = (const float*)d_in[9];
    const float* Uo = (const float*)d_in[10];
    const float* C  = (const float*)d_in[11];
    const float* Cz = (const float*)d_in[12];
    const float* Cr = (const float*)d_in[13];
    const float* Co = (const float*)d_in[14];
    const float* Vo = (const float*)d_in[15];
    const float* Va = (const float*)d_in[16];
    const float* Wa = (const float*)d_in[17];
    const float* Ua = (const float*)d_in[18];

    float* out = (float*)d_out;                // [0,16000) log_sm | [16000,17024) s_new | [17024,119424) alpha
    float* ws  = (float*)d_ws;

    float* acc_r  = ws;            // 1024
    float* acc_z  = ws + 1024;     // 1024
    float* acc_st = ws + 2048;     // 1024
    float* acc_t  = ws + 3072;     // 4096
    float* ws50   = ws + 7168;     // 64 (50 used)
    float* em     = ws + 7232;     // 2560 (2500 used)
    float* cvec   = ws + 9792;     // 2048
    float* rs     = ws + 11840;    // 1024
    float* zbuf   = ws + 12864;    // 1024
    float* snew   = ws + 13888;    // 1024
    float* tvec   = ws + 14912;    // 2048  -> total 16960 floats (~68 KB)

    hipMemsetAsync(ws, 0, 7168 * sizeof(float), stream);  // zero acc_r/z/st/t
    k_phaseA<<<1437, 256, 0, stream>>>(W, Wz, Wr, Uz, Ur, Vo, Wa, y, s,
                                       acc_r, acc_z, acc_st, acc_t, ws50);
    k_escore<<<625, 256, 0, stream>>>(h, Ua, ws50, em);
    k_alpha_c<<<8, 256, 0, stream>>>(h, Va, em, cvec, out + 17024);
    k_phaseB<<<48, 256, 0, stream>>>(C, Cz, Cr, cvec, acc_st, acc_z, acc_r);
    k_rz<<<4, 256, 0, stream>>>(acc_r, acc_z, s, rs, zbuf);
    k_Ust<<<8, 256, 0, stream>>>(U, rs, acc_st);
    k_snew<<<4, 256, 0, stream>>>(acc_st, zbuf, s, snew, out + 16000);
    k_uoco<<<1024, 256, 0, stream>>>(Uo, Co, snew, cvec, acc_t);
    k_tmax<<<8, 256, 0, stream>>>(acc_t, tvec);
    k_wo<<<4000, 256, 0, stream>>>(Wo, tvec, out);
    k_logsm<<<1, 1024, 0, stream>>>(out);
}

// Round 2
// 682.308 us; speedup vs baseline: 1.0126x; 1.0126x over previous
//
#include <hip/hip_runtime.h>
#include <math.h>

#define DEV_INLINE __device__ __forceinline__

DEV_INLINE float sigmoidf_(float x) { return 1.0f / (1.0f + expf(-x)); }

DEV_INLINE float wave_reduce(float v) {
#pragma unroll
    for (int off = 32; off; off >>= 1) v += __shfl_down(v, off, 64);
    return v;
}

// generic wave dot over nv float4 elements, 4 accumulators / 8 loads in flight
DEV_INLINE float wave_dotN(const float* __restrict__ row, const float* __restrict__ x,
                           int nv, int lane) {
    const float4* r4 = (const float4*)row;
    const float4* x4 = (const float4*)x;
    float a0 = 0.f, a1 = 0.f, a2 = 0.f, a3 = 0.f;
    int i = lane;
    for (; i + 192 < nv; i += 256) {
        float4 p0 = r4[i],       q0 = x4[i];
        float4 p1 = r4[i + 64],  q1 = x4[i + 64];
        float4 p2 = r4[i + 128], q2 = x4[i + 128];
        float4 p3 = r4[i + 192], q3 = x4[i + 192];
        a0 = fmaf(p0.x, q0.x, fmaf(p0.y, q0.y, fmaf(p0.z, q0.z, fmaf(p0.w, q0.w, a0))));
        a1 = fmaf(p1.x, q1.x, fmaf(p1.y, q1.y, fmaf(p1.z, q1.z, fmaf(p1.w, q1.w, a1))));
        a2 = fmaf(p2.x, q2.x, fmaf(p2.y, q2.y, fmaf(p2.z, q2.z, fmaf(p2.w, q2.w, a2))));
        a3 = fmaf(p3.x, q3.x, fmaf(p3.y, q3.y, fmaf(p3.z, q3.z, fmaf(p3.w, q3.w, a3))));
    }
    for (; i < nv; i += 64) {
        float4 p = r4[i], q = x4[i];
        a0 = fmaf(p.x, q.x, fmaf(p.y, q.y, fmaf(p.z, q.z, fmaf(p.w, q.w, a0))));
    }
    return wave_reduce(a0 + a1 + a2 + a3);
}

// column-reduction GEMV: out[0..1024) += sum_{r in [r0,r1)} A[r,:] * x[r]
// A row-major (rows x 1024); block=256, thread owns 4 consecutive cols.
// 8-row unroll: 8 independent float4 loads in flight, dual accumulators.
DEV_INLINE void colgemv_block(const float* __restrict__ A, const float* __restrict__ x,
                              float* __restrict__ out, int r0, int r1) {
    int c4 = threadIdx.x;
    const float4* A4 = (const float4*)A;
    float4 s0 = make_float4(0.f, 0.f, 0.f, 0.f);
    float4 s1 = make_float4(0.f, 0.f, 0.f, 0.f);
    int r = r0;
    for (; r + 8 <= r1; r += 8) {
        float4 av[8];
        float xs[8];
#pragma unroll
        for (int k = 0; k < 8; ++k) av[k] = A4[(size_t)(r + k) * 256 + c4];
#pragma unroll
        for (int k = 0; k < 8; ++k) xs[k] = x[r + k];
#pragma unroll
        for (int k = 0; k < 8; ++k) {
            float4 a = av[k];
            float xv = xs[k];
            if (k & 1) {
                s1.x = fmaf(xv, a.x, s1.x); s1.y = fmaf(xv, a.y, s1.y);
                s1.z = fmaf(xv, a.z, s1.z); s1.w = fmaf(xv, a.w, s1.w);
            } else {
                s0.x = fmaf(xv, a.x, s0.x); s0.y = fmaf(xv, a.y, s0.y);
                s0.z = fmaf(xv, a.z, s0.z); s0.w = fmaf(xv, a.w, s0.w);
            }
        }
    }
    for (; r < r1; ++r) {
        float xv = x[r];
        float4 a = A4[(size_t)r * 256 + c4];
        s0.x = fmaf(xv, a.x, s0.x); s0.y = fmaf(xv, a.y, s0.y);
        s0.z = fmaf(xv, a.z, s0.z); s0.w = fmaf(xv, a.w, s0.w);
    }
    int c = c4 * 4;
    atomicAdd(out + c + 0, s0.x + s1.x);
    atomicAdd(out + c + 1, s0.y + s1.y);
    atomicAdd(out + c + 2, s0.z + s1.z);
    atomicAdd(out + c + 3, s0.w + s1.w);
}

// e[i,j] = tanh(Wa[j]@s + Ua[j]@h_i); 50 blocks (one per i), wave per j round-robin
__global__ void k_scores(const float* __restrict__ Wa, const float* __restrict__ Ua,
                         const float* __restrict__ h, const float* __restrict__ s,
                         float* __restrict__ em) {
    int i = blockIdx.x;
    int w = threadIdx.x >> 6, lane = threadIdx.x & 63;
    for (int j = w; j < 50; j += 4) {
        float d1 = wave_dotN(Wa + j * 1024, s, 256, lane);
        float d2 = wave_dotN(Ua + j * 2048, h + i * 2048, 512, lane);
        if (lane == 0) em[i * 50 + j] = tanhf(d1 + d2);
    }
}

// softmax over scores, then alpha + context c. 8 blocks x 256 (covers 2048 cols)
__global__ void k_alpha_c(const float* __restrict__ h, const float* __restrict__ Va,
                          const float* __restrict__ em, float* __restrict__ cvec,
                          float* __restrict__ alpha_out) {
    __shared__ float attn_s[50];
    int tid = threadIdx.x;
    if (tid < 64) {
        float sc = -1e30f;
        if (tid < 50) {
            float t = 0.f;
            for (int j = 0; j < 50; ++j) t = fmaf(Va[j], em[tid * 50 + j], t);
            sc = t;
        }
        float m = sc;
#pragma unroll
        for (int off = 32; off; off >>= 1) m = fmaxf(m, __shfl_xor(m, off, 64));
        float e = (tid < 50) ? expf(sc - m) : 0.f;
        float ssum = e;
#pragma unroll
        for (int off = 32; off; off >>= 1) ssum += __shfl_xor(ssum, off, 64);
        if (tid < 50) attn_s[tid] = e / ssum;
    }
    __syncthreads();
    int g = blockIdx.x * 256 + tid;
    float csum = 0.f;
    for (int i = 0; i < 50; ++i) {
        float a = h[i * 2048 + g] * attn_s[i];
        alpha_out[i * 2048 + g] = a;
        csum += a;
    }
    cvec[g] = csum;
}

// ===== mega kernel: all big weight reads except U (needs r), Uo (needs snew), Wo =====
// [0,128)   W^T y   -> acc_st    (16000x1024, 125 rows/blk)
// [128,256) Wz^T y  -> acc_z
// [256,384) Wr^T y  -> acc_r
// [384,392) Uz^T s  -> acc_z     (1024x1024)
// [392,400) Ur^T s  -> acc_r
// [400,416) C^T c   -> acc_st    (2048x1024)
// [416,432) Cz^T c  -> acc_z
// [432,448) Cr^T c  -> acc_r
// [448,1472) Vo@y + Co@c -> acc_t (4096 rows; wave per row, single writer)
__global__ void k_megaA(const float* __restrict__ W, const float* __restrict__ Wz,
                        const float* __restrict__ Wr, const float* __restrict__ Uz,
                        const float* __restrict__ Ur, const float* __restrict__ C,
                        const float* __restrict__ Cz, const float* __restrict__ Cr,
                        const float* __restrict__ Vo, const float* __restrict__ Co,
                        const float* __restrict__ y, const float* __restrict__ s,
                        const float* __restrict__ cvec, float* acc_r, float* acc_z,
                        float* acc_st, float* acc_t) {
    int b = blockIdx.x;
    if (b < 128) { colgemv_block(W, y, acc_st, b * 125, b * 125 + 125); return; }
    b -= 128;
    if (b < 128) { colgemv_block(Wz, y, acc_z, b * 125, b * 125 + 125); return; }
    b -= 128;
    if (b < 128) { colgemv_block(Wr, y, acc_r, b * 125, b * 125 + 125); return; }
    b -= 128;
    if (b < 8) { colgemv_block(Uz, s, acc_z, b * 128, b * 128 + 128); return; }
    b -= 8;
    if (b < 8) { colgemv_block(Ur, s, acc_r, b * 128, b * 128 + 128); return; }
    b -= 8;
    if (b < 16) { colgemv_block(C, cvec, acc_st, b * 128, b * 128 + 128); return; }
    b -= 16;
    if (b < 16) { colgemv_block(Cz, cvec, acc_z, b * 128, b * 128 + 128); return; }
    b -= 16;
    if (b < 16) { colgemv_block(Cr, cvec, acc_r, b * 128, b * 128 + 128); return; }
    b -= 16;
    {
        int wid = (b * 256 + threadIdx.x) >> 6;   // 0..4095
        int lane = threadIdx.x & 63;
        float v1 = wave_dotN(Vo + (size_t)wid * 16000, y, 4000, lane);
        float v2 = wave_dotN(Co + (size_t)wid * 2048, cvec, 512, lane);
        if (lane == 0) acc_t[wid] = v1 + v2;      // sole writer before k_uoco
    }
}

// r = sigmoid(acc_r); rs = r*s (redundant per block, in LDS); acc_st += U^T rs
__global__ void k_rzUst(const float* __restrict__ U, const float* __restrict__ acc_r,
                        const float* __restrict__ s, float* acc_st) {
    __shared__ float rs_s[1024];
    int tid = threadIdx.x;
#pragma unroll
    for (int k = 0; k < 4; ++k) {
        int n = tid + 256 * k;
        rs_s[n] = sigmoidf_(acc_r[n]) * s[n];
    }
    __syncthreads();
    colgemv_block(U, rs_s, acc_st, blockIdx.x * 128, blockIdx.x * 128 + 128);
}

// snew computed redundantly per block (LDS); acc_t[row] += Uo[row]@snew. 256 blocks.
__global__ void k_uoco_snew(const float* __restrict__ Uo, const float* __restrict__ acc_st,
                            const float* __restrict__ acc_z, const float* __restrict__ s,
                            float* __restrict__ acc_t, float* __restrict__ out_snew) {
    __shared__ float sn[1024];
    int tid = threadIdx.x;
#pragma unroll
    for (int k = 0; k < 4; ++k) {
        int n = tid + 256 * k;
        float z = sigmoidf_(acc_z[n]);
        float st = sigmoidf_(acc_st[n]);
        float v = (1.f - z) * s[n] + z * st;
        sn[n] = v;
        if (blockIdx.x == 0) out_snew[n] = v;
    }
    __syncthreads();
    int w = tid >> 6, lane = tid & 63;
#pragma unroll
    for (int k = 0; k < 4; ++k) {
        int row = blockIdx.x * 16 + w * 4 + k;    // 0..4095
        float d = wave_dotN(Uo + (size_t)row * 1024, sn, 256, lane);
        if (lane == 0) acc_t[row] += d;
    }
}

__global__ void k_tmax(const float* __restrict__ acc_t, float* __restrict__ tvec) {
    int k = blockIdx.x * 256 + threadIdx.x;
    tvec[k] = fmaxf(sigmoidf_(acc_t[2 * k]), sigmoidf_(acc_t[2 * k + 1]));
}

__global__ void k_wo(const float* __restrict__ Wo, const float* __restrict__ tvec,
                     float* __restrict__ logits) {
    int wid = (blockIdx.x * 256 + threadIdx.x) >> 6;
    int lane = threadIdx.x & 63;
    float v = wave_dotN(Wo + (size_t)wid * 2048, tvec, 512, lane);
    if (lane == 0) logits[wid] = v;
}

__global__ void k_logsm(float* __restrict__ out) {
    __shared__ float red[16];
    __shared__ float bval;
    int tid = threadIdx.x, lane = tid & 63, w = tid >> 6;
    float m = -1e30f;
    for (int i = tid; i < 16000; i += 1024) m = fmaxf(m, out[i]);
#pragma unroll
    for (int off = 32; off; off >>= 1) m = fmaxf(m, __shfl_xor(m, off, 64));
    if (lane == 0) red[w] = m;
    __syncthreads();
    if (tid == 0) {
        float mm = red[0];
        for (int i = 1; i < 16; ++i) mm = fmaxf(mm, red[i]);
        bval = mm;
    }
    __syncthreads();
    float M = bval;
    float sum = 0.f;
    for (int i = tid; i < 16000; i += 1024) sum += expf(out[i] - M);
#pragma unroll
    for (int off = 32; off; off >>= 1) sum += __shfl_xor(sum, off, 64);
    if (lane == 0) red[w] = sum;
    __syncthreads();
    if (tid == 0) {
        float ss = 0.f;
        for (int i = 0; i < 16; ++i) ss += red[i];
        bval = M + logf(ss);
    }
    __syncthreads();
    float lse = bval;
    for (int i = tid; i < 16000; i += 1024) out[i] -= lse;
}

extern "C" void kernel_launch(void* const* d_in, const int* in_sizes, int n_in,
                              void* d_out, int out_size, void* d_ws, size_t ws_size,
                              hipStream_t stream) {
    const float* y  = (const float*)d_in[0];
    const float* s  = (const float*)d_in[1];
    const float* h  = (const float*)d_in[2];
    const float* W  = (const float*)d_in[3];
    const float* Wz = (const float*)d_in[4];
    const float* Wr = (const float*)d_in[5];
    const float* Wo = (const float*)d_in[6];
    const float* U  = (const float*)d_in[7];
    const float* Uz = (const float*)d_in[8];
    const float* Ur = (const float*)d_in[9];
    const float* Uo = (const float*)d_in[10];
    const float* C  = (const float*)d_in[11];
    const float* Cz = (const float*)d_in[12];
    const float* Cr = (const float*)d_in[13];
    const float* Co = (const float*)d_in[14];
    const float* Vo = (const float*)d_in[15];
    const float* Va = (const float*)d_in[16];
    const float* Wa = (const float*)d_in[17];
    const float* Ua = (const float*)d_in[18];

    float* out = (float*)d_out;   // [0,16000) log_sm | [16000,17024) s_new | [17024,119424) alpha
    float* ws  = (float*)d_ws;

    float* acc_r  = ws;            // 1024 (atomic -> zero)
    float* acc_z  = ws + 1024;     // 1024 (atomic -> zero)
    float* acc_st = ws + 2048;     // 1024 (atomic -> zero)
    float* acc_t  = ws + 3072;     // 4096 (overwritten by megaA)
    float* em     = ws + 7168;     // 2560 (2500 used)
    float* cvec   = ws + 9728;     // 2048
    float* tvec   = ws + 11776;    // 2048

    hipMemsetAsync(ws, 0, 3072 * sizeof(float), stream);
    k_scores<<<50, 256, 0, stream>>>(Wa, Ua, h, s, em);
    k_alpha_c<<<8, 256, 0, stream>>>(h, Va, em, cvec, out + 17024);
    k_megaA<<<1472, 256, 0, stream>>>(W, Wz, Wr, Uz, Ur, C, Cz, Cr, Vo, Co,
                                      y, s, cvec, acc_r, acc_z, acc_st, acc_t);
    k_rzUst<<<8, 256, 0, stream>>>(U, acc_r, s, acc_st);
    k_uoco_snew<<<256, 256, 0, stream>>>(Uo, acc_st, acc_z, s, acc_t, out + 16000);
    k_tmax<<<8, 256, 0, stream>>>(acc_t, tvec);
    k_wo<<<4000, 256, 0, stream>>>(Wo, tvec, out);
    k_logsm<<<1, 1024, 0, stream>>>(out);
}